// Round 1
// baseline (97.194 us; speedup 1.0000x reference)
//
#include <hip/hip_runtime.h>

// cov = L L^T with L = R(q) * diag(exp(s)); cov[i][j] = sum_k R[i][k]R[j][k]exp(2 s[k])
// 4 points per thread => all global accesses are aligned float4 (16B/lane).

__global__ __launch_bounds__(256) void gauss_cov_kernel(
    const float* __restrict__ scales,   // N*3
    const float* __restrict__ rot,      // N*4
    float* __restrict__ out,            // N*9
    int nquad)                          // N/4
{
    int t = blockIdx.x * blockDim.x + threadIdx.x;
    const int stride = gridDim.x * blockDim.x;
    const float4* __restrict__ sc4 = (const float4*)scales;
    const float4* __restrict__ rt4 = (const float4*)rot;
    float4* __restrict__ o4 = (float4*)out;

    for (; t < nquad; t += stride) {
        // 12 scale floats for points 4t..4t+3
        float s[12];
        {
            float4 a = sc4[3 * t + 0];
            float4 b = sc4[3 * t + 1];
            float4 c = sc4[3 * t + 2];
            s[0] = a.x; s[1] = a.y; s[2]  = a.z; s[3]  = a.w;
            s[4] = b.x; s[5] = b.y; s[6]  = b.z; s[7]  = b.w;
            s[8] = c.x; s[9] = c.y; s[10] = c.z; s[11] = c.w;
        }

        float o[36];
#pragma unroll
        for (int p = 0; p < 4; ++p) {
            float4 q = rt4[4 * t + p];
            float w = q.x, x = q.y, y = q.z, z = q.w;
            float n2 = w * w + x * x + y * y + z * z;
            float inv = 1.0f / (sqrtf(n2) + 1e-8f);
            w *= inv; x *= inv; y *= inv; z *= inv;

            float R00 = 1.0f - 2.0f * (y * y + z * z);
            float R01 = 2.0f * (x * y - z * w);
            float R02 = 2.0f * (x * z + y * w);
            float R10 = 2.0f * (x * y + z * w);
            float R11 = 1.0f - 2.0f * (x * x + z * z);
            float R12 = 2.0f * (y * z - x * w);
            float R20 = 2.0f * (x * z - y * w);
            float R21 = 2.0f * (y * z + x * w);
            float R22 = 1.0f - 2.0f * (x * x + y * y);

            float e0 = __expf(2.0f * s[3 * p + 0]);
            float e1 = __expf(2.0f * s[3 * p + 1]);
            float e2 = __expf(2.0f * s[3 * p + 2]);

            float c00 = R00 * R00 * e0 + R01 * R01 * e1 + R02 * R02 * e2;
            float c01 = R00 * R10 * e0 + R01 * R11 * e1 + R02 * R12 * e2;
            float c02 = R00 * R20 * e0 + R01 * R21 * e1 + R02 * R22 * e2;
            float c11 = R10 * R10 * e0 + R11 * R11 * e1 + R12 * R12 * e2;
            float c12 = R10 * R20 * e0 + R11 * R21 * e1 + R12 * R22 * e2;
            float c22 = R20 * R20 * e0 + R21 * R21 * e1 + R22 * R22 * e2;

            float* op = &o[9 * p];
            op[0] = c00; op[1] = c01; op[2] = c02;
            op[3] = c01; op[4] = c11; op[5] = c12;
            op[6] = c02; op[7] = c12; op[8] = c22;
        }

        // 36 floats -> 9 aligned float4 stores
#pragma unroll
        for (int j = 0; j < 9; ++j) {
            o4[9 * t + j] = make_float4(o[4 * j + 0], o[4 * j + 1],
                                        o[4 * j + 2], o[4 * j + 3]);
        }
    }
}

extern "C" void kernel_launch(void* const* d_in, const int* in_sizes, int n_in,
                              void* d_out, int out_size, void* d_ws, size_t ws_size,
                              hipStream_t stream) {
    const float* scales = (const float*)d_in[0];
    const float* rot    = (const float*)d_in[1];
    float* out          = (float*)d_out;

    const int N = in_sizes[0] / 3;     // 4,000,000
    const int nquad = N / 4;           // 1,000,000 (N divisible by 4)

    const int block = 256;
    int grid = (nquad + block - 1) / block;
    if (grid > 8192) grid = 8192;

    gauss_cov_kernel<<<grid, block, 0, stream>>>(scales, rot, out, nquad);
}

// Round 2
// 43.832 us; speedup vs baseline: 2.2174x; 2.2174x over previous
//
#include <hip/hip_runtime.h>

// cov = L L^T, L = R(q) * diag(exp(s)); cov[i][j] = sum_k R[i][k]R[j][k]exp(2 s[k])
// One point per thread. LDS staging so ALL global traffic is contiguous float4:
//   scales  : 192 float4 coalesced loads -> LDS -> stride-3 scalar LDS reads (conflict-free)
//   rot     : direct float4 loads (naturally coalesced)
//   out     : 9 floats -> LDS (stride 9, gcd(9,32)=1 -> conflict-free) -> 576 contiguous float4 stores

__global__ __launch_bounds__(256) void gauss_cov_kernel(
    const float4* __restrict__ sc4,   // scales as float4, N*3/4 entries
    const float4* __restrict__ rt4,   // rotations as float4, N entries
    float4* __restrict__ o4)          // output as float4, N*9/4 entries
{
    __shared__ float s_sc[768];       // 256 points * 3 floats
    __shared__ float s_out[2304];     // 256 points * 9 floats

    const int tid  = threadIdx.x;
    const int blk  = blockIdx.x;
    const int base = blk * 256;       // first point of this block

    // --- stage scales: 768 floats = 192 float4, fully coalesced ---
    if (tid < 192) {
        ((float4*)s_sc)[tid] = sc4[blk * 192 + tid];
    }
    // --- rotations: direct coalesced float4 ---
    float4 q = rt4[base + tid];
    __syncthreads();

    float s0 = s_sc[3 * tid + 0];
    float s1 = s_sc[3 * tid + 1];
    float s2 = s_sc[3 * tid + 2];

    float w = q.x, x = q.y, y = q.z, z = q.w;
    float n2  = w * w + x * x + y * y + z * z;
    float inv = 1.0f / (sqrtf(n2) + 1e-8f);
    w *= inv; x *= inv; y *= inv; z *= inv;

    float R00 = 1.0f - 2.0f * (y * y + z * z);
    float R01 = 2.0f * (x * y - z * w);
    float R02 = 2.0f * (x * z + y * w);
    float R10 = 2.0f * (x * y + z * w);
    float R11 = 1.0f - 2.0f * (x * x + z * z);
    float R12 = 2.0f * (y * z - x * w);
    float R20 = 2.0f * (x * z - y * w);
    float R21 = 2.0f * (y * z + x * w);
    float R22 = 1.0f - 2.0f * (x * x + y * y);

    float e0 = __expf(2.0f * s0);
    float e1 = __expf(2.0f * s1);
    float e2 = __expf(2.0f * s2);

    float c00 = R00 * R00 * e0 + R01 * R01 * e1 + R02 * R02 * e2;
    float c01 = R00 * R10 * e0 + R01 * R11 * e1 + R02 * R12 * e2;
    float c02 = R00 * R20 * e0 + R01 * R21 * e1 + R02 * R22 * e2;
    float c11 = R10 * R10 * e0 + R11 * R11 * e1 + R12 * R12 * e2;
    float c12 = R10 * R20 * e0 + R11 * R21 * e1 + R12 * R22 * e2;
    float c22 = R20 * R20 * e0 + R21 * R21 * e1 + R22 * R22 * e2;

    float* o = &s_out[tid * 9];
    o[0] = c00; o[1] = c01; o[2] = c02;
    o[3] = c01; o[4] = c11; o[5] = c12;
    o[6] = c02; o[7] = c12; o[8] = c22;
    __syncthreads();

    // --- cooperative contiguous store: 2304 floats = 576 float4 per block ---
    const float4* l4  = (const float4*)s_out;
    float4*       dst = o4 + (size_t)blk * 576;
    dst[tid]       = l4[tid];
    dst[tid + 256] = l4[tid + 256];
    if (tid < 64) dst[tid + 512] = l4[tid + 512];
}

extern "C" void kernel_launch(void* const* d_in, const int* in_sizes, int n_in,
                              void* d_out, int out_size, void* d_ws, size_t ws_size,
                              hipStream_t stream) {
    const float4* sc4 = (const float4*)d_in[0];
    const float4* rt4 = (const float4*)d_in[1];
    float4* o4        = (float4*)d_out;

    const int N = in_sizes[0] / 3;     // 4,000,000 (divisible by 256)
    const int grid = N / 256;          // 15625 blocks

    gauss_cov_kernel<<<grid, 256, 0, stream>>>(sc4, rt4, o4);
}